// Round 5
// baseline (11172.842 us; speedup 1.0000x reference)
//
#include <hip/hip_runtime.h>

#define DH 256
#define DS 552
#define DS_PAD 576
#define NG 1024
#define LTOK 128
#define STEPS_DEC 1000
#define ST_TRUE 800
#define TOTAL_STEPS (LTOK + STEPS_DEC)
#define NREC 16
#define GRID_BLKS 128
#define NHELP (GRID_BLKS - NREC)
#define LDG 68    // G LDS stride (floats)
#define LDH 264   // hid/sh LDS stride (shorts)

typedef __attribute__((ext_vector_type(8))) short bf16x8;
typedef __attribute__((ext_vector_type(4))) float f32x4;

// ---------- workspace layout (bytes) ----------
// flags page (0..4095):
//   flags[0..15]   : u32, bytes 0..63 -- ONE cacheline, coalesced poll
//   gstep replicas : 8 x u32 at byte 3072 + i*128 (u32 idx 768 + i*32)
// gxd page (4096..8191): gxdone 800 x u32 @ byte 4096
#define OFF_FLAGS    0
#define OFF_GXD      4096
#define OFF_HPL      8192         // h planes [2 pl][2 half][64][256] bf16 = 131072
#define OFF_WHE_HI   139264
#define OFF_WHE_LO   663552
#define OFF_WHD_HI   1187840
#define OFF_WHD_LO   1712128
#define OFF_WC_HI    2236416      // [1024][576]
#define OFF_WC_LO    3416064
#define OFF_W1_HI    4595712
#define OFF_W1_LO    4726784
#define OFF_W2_HI    4857856      // [576][256] (rows 552.. zero)
#define OFF_W2_LO    5152768
#define OFF_SW1_HI   5447680
#define OFF_SW1_LO   5578752
#define OFF_EMB2     5709824      // [148][1024] f32
#define OFF_BCOMB    6316032
#define OFF_WCF      6320128      // [1024][552] f32 scratch
#define OFF_HBF      8581120      // [1000][64][256] bf16
#define OFF_GX       41349120     // [800][64][1024] fp16
#define WS_NEED      146206720ULL

__device__ __forceinline__ unsigned short f2bf_rn(float x) {
  unsigned u = __builtin_bit_cast(unsigned, x);
  u += 0x7fffu + ((u >> 16) & 1u);
  return (unsigned short)(u >> 16);
}
__device__ __forceinline__ float bf2f(unsigned short h) {
  unsigned u = ((unsigned)h) << 16;
  return __builtin_bit_cast(float, u);
}
__device__ __forceinline__ f32x4 mfma16(bf16x8 a, bf16x8 b, f32x4 c) {
  return __builtin_amdgcn_mfma_f32_16x16x32_bf16(a, b, c, 0, 0, 0);
}

// ---------- MALL (agent coherence point) helpers -- round-2 proven ----------
__device__ __forceinline__ unsigned long long ald8(const void* p) {
  return __hip_atomic_load((unsigned long long*)p, __ATOMIC_RELAXED,
                           __HIP_MEMORY_SCOPE_AGENT);
}
__device__ __forceinline__ void ast8(void* p, unsigned long long v) {
  __hip_atomic_store((unsigned long long*)p, v, __ATOMIC_RELAXED,
                     __HIP_MEMORY_SCOPE_AGENT);
}
__device__ __forceinline__ bf16x8 ald16v(const unsigned short* p) {
  union { unsigned long long u[2]; bf16x8 v; } t;
  t.u[0] = ald8(p);
  t.u[1] = ald8(p + 4);
  return t.v;
}
__device__ __forceinline__ unsigned long long pack64(unsigned lo, unsigned hi) {
  return (unsigned long long)lo | ((unsigned long long)hi << 32);
}

// ---------- prep kernels (unchanged) ----------
__global__ __launch_bounds__(256) void prep_wcomb_kernel(
    const float* __restrict__ Wih, const float* __restrict__ preW,
    const float* __restrict__ pre_b, const float* __restrict__ bih,
    const float* __restrict__ bhh, float* __restrict__ WcombF,
    float* __restrict__ bcomb) {
  __shared__ float row[DH];
  __shared__ float red[256];
  int g = blockIdx.x, tid = threadIdx.x;
  row[tid] = Wih[g * DH + tid];
  __syncthreads();
  float a0 = 0.f, a1 = 0.f, a2 = 0.f;
  for (int j = 0; j < DH; ++j) {
    float wv = row[j];
    const float* pr = preW + j * DS;
    a0 += wv * pr[tid];
    a1 += wv * pr[tid + 256];
    if (tid < DS - 512) a2 += wv * pr[tid + 512];
  }
  WcombF[g * DS + tid] = a0;
  WcombF[g * DS + tid + 256] = a1;
  if (tid < DS - 512) WcombF[g * DS + tid + 512] = a2;
  red[tid] = row[tid] * pre_b[tid];
  __syncthreads();
  for (int s = 128; s > 0; s >>= 1) {
    if (tid < s) red[tid] += red[tid + s];
    __syncthreads();
  }
  if (tid == 0) bcomb[g] = red[0] + bih[g] + bhh[g];
}

__global__ __launch_bounds__(256) void prep_emb2_kernel(
    const float* __restrict__ emb, const float* __restrict__ Wih,
    const float* __restrict__ bih, const float* __restrict__ bhh,
    float* __restrict__ emb2) {
  __shared__ float erow[DH];
  int v = blockIdx.x, tid = threadIdx.x;
  erow[tid] = emb[v * DH + tid];
  __syncthreads();
  for (int c = 0; c < 4; ++c) {
    int g = c * 256 + tid;
    const float* wr = Wih + g * DH;
    float acc = 0.f;
    for (int j = 0; j < DH; ++j) acc += erow[j] * wr[j];
    emb2[v * NG + g] = acc + bih[g] + bhh[g];
  }
}

__global__ void split_bf16_kernel(const float* __restrict__ src,
                                  unsigned short* __restrict__ hi,
                                  unsigned short* __restrict__ lo,
                                  int rows, int cols, int ldo) {
  int idx = blockIdx.x * 256 + threadIdx.x;
  if (idx >= rows * cols) return;
  int r = idx / cols, c = idx - r * cols;
  float x = src[idx];
  unsigned short h = f2bf_rn(x);
  hi[r * ldo + c] = h;
  lo[r * ldo + c] = f2bf_rn(x - bf2f(h));
}

// ---------- shared memory union ----------
union SharedU {
  struct { float G[64 * LDG]; } rec;
  struct {
    unsigned short hid[64 * LDH];
    unsigned short sh[64 * LDH];
    float red[256];
  } post;
};

// ---------- mega kernel: 16 recurrence blocks + 112 helper blocks ----------
// Round-2's proven MALL protocol, with contention removed:
//  - flags packed into ONE 64B line (coalesced poll, one MALL txn per poll)
//  - only wave 0 of each rec block polls; __syncthreads releases the rest
//  - helpers poll 8 replicated gstep lines (fanned out by rec block 0)
//    instead of the flag line: flag-line traffic drops ~80x.
__global__ __launch_bounds__(256, 1) void mega_kernel(
    const unsigned short* __restrict__ whe_hi, const unsigned short* __restrict__ whe_lo,
    const unsigned short* __restrict__ whd_hi, const unsigned short* __restrict__ whd_lo,
    const unsigned short* __restrict__ wc_hi, const unsigned short* __restrict__ wc_lo,
    const unsigned short* __restrict__ w1_hi, const unsigned short* __restrict__ w1_lo,
    const unsigned short* __restrict__ w2_hi, const unsigned short* __restrict__ w2_lo,
    const unsigned short* __restrict__ sw1_hi, const unsigned short* __restrict__ sw1_lo,
    const float* __restrict__ emb2, const float* __restrict__ bcomb,
    const int* __restrict__ token_pad, const int* __restrict__ token_len,
    const float* __restrict__ Strue,
    const float* __restrict__ post_b1, const float* __restrict__ post_b2,
    const float* __restrict__ stop_b1, const float* __restrict__ stop_w2,
    const float* __restrict__ stop_b2,
    unsigned short* __restrict__ hpl, unsigned short* __restrict__ Hbf,
    _Float16* __restrict__ gx, unsigned* flags, unsigned* gxdone,
    float* __restrict__ outS, float* __restrict__ outStop) {
  __shared__ SharedU smem;
  int tid = threadIdx.x;
  int w = tid >> 6, lane = tid & 63, quad = lane >> 4, lrow = lane & 15;

  if (blockIdx.x < NREC) {
    // ================= persistent recurrence =================
    int rb = blockIdx.x;
    int b = lane;                 // nonlin batch role
    int u0 = w * 4;               // 4 local units per thread (contiguous)
    int gub = 16 * rb + u0;       // global unit base
    int len = token_len[b];
    float bc[16];
#pragma unroll
    for (int i = 0; i < 4; ++i)
#pragma unroll
      for (int g = 0; g < 4; ++g) bc[i * 4 + g] = bcomb[g * 256 + gub + i];
    // B-frags (weights) fully in VGPRs: n-tile j, lane lrow -> nloc = 16j+lrow
    int grow0 = (lrow & 3) * 256 + 16 * rb + (lrow >> 2);
    bf16x8 Bh[4][8], Bl[4][8];
#pragma unroll
    for (int j = 0; j < 4; ++j)
#pragma unroll
      for (int ks = 0; ks < 8; ++ks) {
        size_t off = (size_t)(grow0 + 4 * j) * DH + ks * 32 + quad * 8;
        Bh[j][ks] = *(const bf16x8*)(whe_hi + off);
        Bl[j][ks] = *(const bf16x8*)(whe_lo + off);
      }
    float c[4] = {0.f, 0.f, 0.f, 0.f}, h[4] = {0.f, 0.f, 0.f, 0.f};
    float xc[16], xn[16];
    {  // x for S=0 (encoder)
      int tok = token_pad[b];
#pragma unroll
      for (int g = 0; g < 4; ++g) {
        float4 e = *(const float4*)(emb2 + (size_t)tok * NG + g * 256 + gub);
        xc[0 * 4 + g] = e.x; xc[1 * 4 + g] = e.y;
        xc[2 * 4 + g] = e.z; xc[3 * 4 + g] = e.w;
      }
    }
    int gxwm = 0;  // maintained by wave 0 only
    float* G = smem.rec.G;
    for (int S = 0; S < TOTAL_STEPS; ++S) {
      if (S == LTOK) {  // swap to decoder weights; (h,c) = (enc_out, enc_out)
#pragma unroll
        for (int j = 0; j < 4; ++j)
#pragma unroll
          for (int ks = 0; ks < 8; ++ks) {
            size_t off = (size_t)(grow0 + 4 * j) * DH + ks * 32 + quad * 8;
            Bh[j][ks] = *(const bf16x8*)(whd_hi + off);
            Bl[j][ks] = *(const bf16x8*)(whd_lo + off);
          }
#pragma unroll
        for (int i = 0; i < 4; ++i) c[i] = h[i];
      }
      int dn = S + 1 - LTOK;  // decoder index of NEXT step's x
      // 1. wave 0: gx readiness + peer flags >= S, then release the block.
      if (w == 0) {
        if (dn >= 1 && dn < ST_TRUE) {
          while (gxwm < dn) {
            if (__hip_atomic_load(&gxdone[gxwm + 1], __ATOMIC_RELAXED,
                                  __HIP_MEMORY_SCOPE_AGENT) >= 16u)
              ++gxwm;
            else
              __builtin_amdgcn_s_sleep(1);
          }
        }
        const unsigned* fp = &flags[lane & 15];  // one 64B line, coalesced
        unsigned tgt = (unsigned)S;
        for (;;) {
          unsigned f =
              __hip_atomic_load(fp, __ATOMIC_RELAXED, __HIP_MEMORY_SCOPE_AGENT);
          if (__all(f >= tgt)) break;
          __builtin_amdgcn_s_sleep(1);
        }
        // block 0 fans the aggregated step out to 8 replicated gstep lines
        // (helpers poll those, never the flag line)
        if (rb == 0 && lane == 0 && S > LTOK) {
#pragma unroll
          for (int i = 0; i < 8; ++i)
            __hip_atomic_store(&flags[768 + i * 32], (unsigned)S,
                               __ATOMIC_RELAXED, __HIP_MEMORY_SCOPE_AGENT);
        }
      }
      __syncthreads();
      asm volatile("" ::: "memory");
      // 2. A-frags (h hi/lo) -- MALL-direct loads (bypass stale L1/L2)
      const unsigned short* hb = hpl + ((S & 1) << 15);
      int arow = w * 16 + lrow;
      bf16x8 Ah[8], Al[8];
#pragma unroll
      for (int ks = 0; ks < 8; ++ks) {
        Ah[ks] = ald16v(hb + arow * 256 + ks * 32 + quad * 8);
        Al[ks] = ald16v(hb + 16384 + arow * 256 + ks * 32 + quad * 8);
      }
      // 3. prefetch x for step S+1 (overlaps A-frag latency + MFMA)
      if (S + 1 < LTOK) {
        int tok = token_pad[(S + 1) * 64 + b];
#pragma unroll
        for (int g = 0; g < 4; ++g) {
          float4 e = *(const float4*)(emb2 + (size_t)tok * NG + g * 256 + gub);
          xn[0 * 4 + g] = e.x; xn[1 * 4 + g] = e.y;
          xn[2 * 4 + g] = e.z; xn[3 * 4 + g] = e.w;
        }
      } else if (dn >= 1 && dn < ST_TRUE) {
        const _Float16* gp = gx + ((size_t)dn * 64 + b) * NG;
#pragma unroll
        for (int g = 0; g < 4; ++g) {
          union { unsigned long long u; _Float16 f[4]; } t;
          t.u = ald8(gp + g * 256 + gub);
#pragma unroll
          for (int i = 0; i < 4; ++i) xn[i * 4 + g] = (float)t.f[i];
        }
      } else {
#pragma unroll
        for (int k = 0; k < 16; ++k) xn[k] = 0.f;
      }
      // 4. MFMA: G-slice 64x64, 3-term split
      f32x4 acc[4];
#pragma unroll
      for (int j = 0; j < 4; ++j) acc[j] = (f32x4){0.f, 0.f, 0.f, 0.f};
#pragma unroll
      for (int ks = 0; ks < 8; ++ks)
#pragma unroll
        for (int j = 0; j < 4; ++j) {
          acc[j] = mfma16(Ah[ks], Bh[j][ks], acc[j]);
          acc[j] = mfma16(Al[ks], Bh[j][ks], acc[j]);
          acc[j] = mfma16(Ah[ks], Bl[j][ks], acc[j]);
        }
      // 5. G -> LDS  (layout [nloc][b])
#pragma unroll
      for (int j = 0; j < 4; ++j)
        *(f32x4*)&G[(16 * j + lrow) * LDG + 16 * w + quad * 4] = acc[j];
      __syncthreads();
      // 6. nonlinearity: 4 cells (b, gub..gub+3)
      unsigned hv0, hv1, lv0, lv1;
      {
        unsigned short hhs[4], hls[4];
#pragma unroll
        for (int i = 0; i < 4; ++i) {
          float gI = G[(4 * (u0 + i) + 0) * LDG + b];
          float gF = G[(4 * (u0 + i) + 1) * LDG + b];
          float gG = G[(4 * (u0 + i) + 2) * LDG + b];
          float gO = G[(4 * (u0 + i) + 3) * LDG + b];
          if (S < LTOK) {
            gI += xc[i * 4 + 0]; gF += xc[i * 4 + 1];
            gG += xc[i * 4 + 2]; gO += xc[i * 4 + 3];
          } else {
            gI += bc[i * 4 + 0] + xc[i * 4 + 0];
            gF += bc[i * 4 + 1] + xc[i * 4 + 1];
            gG += bc[i * 4 + 2] + xc[i * 4 + 2];
            gO += bc[i * 4 + 3] + xc[i * 4 + 3];
          }
          float si = 1.f / (1.f + expf(-gI));
          float sf = 1.f / (1.f + expf(-gF));
          float so = 1.f / (1.f + expf(-gO));
          float c2 = sf * c[i] + si * tanhf(gG);
          float h2 = so * tanhf(c2);
          if (S < LTOK && S >= len) { c2 = c[i]; h2 = h[i]; }
          c[i] = c2; h[i] = h2;
          unsigned short hh = f2bf_rn(h2);
          hhs[i] = hh;
          hls[i] = f2bf_rn(h2 - bf2f(hh));
        }
        hv0 = (unsigned)hhs[0] | ((unsigned)hhs[1] << 16);
        hv1 = (unsigned)hhs[2] | ((unsigned)hhs[3] << 16);
        lv0 = (unsigned)hls[0] | ((unsigned)hls[1] << 16);
        lv1 = (unsigned)hls[2] | ((unsigned)hls[3] << 16);
      }
      // 7. publish h (MALL-direct write-through) + Hbf
      unsigned short* ob = hpl + (((S & 1) ^ 1) << 15);
      ast8(&ob[b * 256 + gub], pack64(hv0, hv1));
      ast8(&ob[16384 + b * 256 + gub], pack64(lv0, lv1));
      if (S >= LTOK) {
        int d = S - LTOK;
        ast8(&Hbf[((size_t)d * 64 + b) * 256 + gub], pack64(hv0, hv1));
      }
#pragma unroll
      for (int k = 0; k < 16; ++k) xc[k] = xn[k];
      // 8. __syncthreads drains each wave's vmcnt (write-through stores reach
      // the coherence point) and protects G reuse; then publish flag.
      __syncthreads();
      if (tid == 0)
        __hip_atomic_store(&flags[rb], (unsigned)(S + 1), __ATOMIC_RELAXED,
                           __HIP_MEMORY_SCOPE_AGENT);
    }
    // epilogue: block 0 releases helpers for the final steps
    if (rb == 0 && w == 0) {
      const unsigned* fp = &flags[lane & 15];
      unsigned tgt = (unsigned)TOTAL_STEPS;
      for (;;) {
        unsigned f =
            __hip_atomic_load(fp, __ATOMIC_RELAXED, __HIP_MEMORY_SCOPE_AGENT);
        if (__all(f >= tgt)) break;
        __builtin_amdgcn_s_sleep(2);
      }
      if (lane == 0) {
#pragma unroll
        for (int i = 0; i < 8; ++i)
          __hip_atomic_store(&flags[768 + i * 32], (unsigned)TOTAL_STEPS,
                             __ATOMIC_RELAXED, __HIP_MEMORY_SCOPE_AGENT);
      }
    }
  } else {
    // ================= helpers =================
    int hid0 = blockIdx.x - NREC;
    // ---- phase 1: gx tiles (t ascending) ----
    for (int item = hid0; item < 799 * 16; item += NHELP) {
      int t = 1 + (item >> 4);
      int n0 = (item & 15) << 6;
      f32x4 acc[4];
#pragma unroll
      for (int j = 0; j < 4; ++j) acc[j] = (f32x4){0.f, 0.f, 0.f, 0.f};
      for (int ks = 0; ks < 18; ++ks) {
        int kb = ks * 32 + quad * 8;
        bf16x8 ah, al;
        if (kb < DS) {
          const float* ap = Strue + ((size_t)t * 64 + w * 16 + lrow) * DS + kb;
          float4 x0 = *(const float4*)ap;
          float4 x1 = *(const float4*)(ap + 4);
          float xs[8] = {x0.x, x0.y, x0.z, x0.w, x1.x, x1.y, x1.z, x1.w};
#pragma unroll
          for (int j = 0; j < 8; ++j) {
            unsigned u = __builtin_bit_cast(unsigned, xs[j]);
            unsigned short hh = (unsigned short)(u >> 16);
            ah[j] = (short)hh;
            al[j] = (short)f2bf_rn(xs[j] - bf2f(hh));
          }
        } else {
#pragma unroll
          for (int j = 0; j < 8; ++j) { ah[j] = 0; al[j] = 0; }
        }
#pragma unroll
        for (int j = 0; j < 4; ++j) {
          int n = n0 + j * 16 + lrow;
          bf16x8 bh = *(const bf16x8*)(wc_hi + (size_t)n * DS_PAD + kb);
          bf16x8 bl = *(const bf16x8*)(wc_lo + (size_t)n * DS_PAD + kb);
          acc[j] = mfma16(ah, bh, acc[j]);
          acc[j] = mfma16(al, bh, acc[j]);
          acc[j] = mfma16(ah, bl, acc[j]);
        }
      }
#pragma unroll
      for (int j = 0; j < 4; ++j) {
        int n = n0 + j * 16 + lrow;
#pragma unroll
        for (int r = 0; r < 4; ++r)
          gx[((size_t)t * 64 + w * 16 + quad * 4 + r) * NG + n] =
              (_Float16)acc[j][r];
      }
      __syncthreads();
      if (tid == 0) {
        __builtin_amdgcn_fence(__ATOMIC_RELEASE, "agent");
        __hip_atomic_fetch_add(&gxdone[t], 1u, __ATOMIC_RELAXED,
                               __HIP_MEMORY_SCOPE_AGENT);
      }
      __syncthreads();
    }
    // ---- phase 2: post-nets per decoder step ----
    const unsigned* gs = &flags[768 + (blockIdx.x & 7) * 32];  // replica
    for (int d = hid0; d < STEPS_DEC; d += NHELP) {
      unsigned tgt = (unsigned)(LTOK + d + 1);
      if (w == 0) {
        for (;;) {
          unsigned g = __hip_atomic_load(gs, __ATOMIC_RELAXED,
                                         __HIP_MEMORY_SCOPE_AGENT);
          if (g >= tgt) break;
          __builtin_amdgcn_s_sleep(32);
        }
      }
      __syncthreads();
      asm volatile("" ::: "memory");
      // A-frags from Hbf[d] -- MALL-direct (producer published write-through)
      bf16x8 Af[8];
#pragma unroll
      for (int ks = 0; ks < 8; ++ks)
        Af[ks] = ald16v(Hbf + ((size_t)d * 64 + w * 16 + lrow) * 256 +
                        ks * 32 + quad * 8);
      // W1 -> hid (LDS), relu, bf16
      {
        f32x4 a1[16];
#pragma unroll
        for (int j = 0; j < 16; ++j) a1[j] = (f32x4){0.f, 0.f, 0.f, 0.f};
        for (int ks = 0; ks < 8; ++ks) {
          int kb = ks * 32 + quad * 8;
#pragma unroll
          for (int j = 0; j < 16; ++j) {
            int n = j * 16 + lrow;
            bf16x8 bh = *(const bf16x8*)(w1_hi + (size_t)n * DH + kb);
            bf16x8 bl = *(const bf16x8*)(w1_lo + (size_t)n * DH + kb);
            a1[j] = mfma16(Af[ks], bh, a1[j]);
            a1[j] = mfma16(Af[ks], bl, a1[j]);
          }
        }
#pragma unroll
        for (int j = 0; j < 16; ++j) {
          int n = j * 16 + lrow;
          float bv = post_b1[n];
#pragma unroll
          for (int r = 0; r < 4; ++r) {
            float v = fmaxf(a1[j][r] + bv, 0.f);
            smem.post.hid[(16 * w + quad * 4 + r) * LDH + n] = f2bf_rn(v);
          }
        }
        // SW1 -> sh (LDS)
#pragma unroll
        for (int j = 0; j < 16; ++j) a1[j] = (f32x4){0.f, 0.f, 0.f, 0.f};
        for (int ks = 0; ks < 8; ++ks) {
          int kb = ks * 32 + quad * 8;
#pragma unroll
          for (int j = 0; j < 16; ++j) {
            int n = j * 16 + lrow;
            bf16x8 bh = *(const bf16x8*)(sw1_hi + (size_t)n * DH + kb);
            bf16x8 bl = *(const bf16x8*)(sw1_lo + (size_t)n * DH + kb);
            a1[j] = mfma16(Af[ks], bh, a1[j]);
            a1[j] = mfma16(Af[ks], bl, a1[j]);
          }
        }
#pragma unroll
        for (int j = 0; j < 16; ++j) {
          int n = j * 16 + lrow;
          float bv = stop_b1[n];
#pragma unroll
          for (int r = 0; r < 4; ++r) {
            float v = fmaxf(a1[j][r] + bv, 0.f);
            smem.post.sh[(16 * w + quad * 4 + r) * LDH + n] = f2bf_rn(v);
          }
        }
      }
      __syncthreads();
      // W2: hid @ W2^T + b2 -> outS (fp32)
      {
        bf16x8 Hf[8];
#pragma unroll
        for (int ks = 0; ks < 8; ++ks)
          Hf[ks] = *(const bf16x8*)&smem.post
                        .hid[(16 * w + lrow) * LDH + ks * 32 + quad * 8];
        f32x4 a2[36];
#pragma unroll
        for (int j = 0; j < 36; ++j) a2[j] = (f32x4){0.f, 0.f, 0.f, 0.f};
        for (int ks = 0; ks < 8; ++ks) {
          int kb = ks * 32 + quad * 8;
#pragma unroll
          for (int j = 0; j < 36; ++j) {
            int n = j * 16 + lrow;
            bf16x8 bh = *(const bf16x8*)(w2_hi + (size_t)n * DH + kb);
            bf16x8 bl = *(const bf16x8*)(w2_lo + (size_t)n * DH + kb);
            a2[j] = mfma16(Hf[ks], bh, a2[j]);
            a2[j] = mfma16(Hf[ks], bl, a2[j]);
          }
        }
#pragma unroll
        for (int j = 0; j < 36; ++j) {
          int n = j * 16 + lrow;
          if (n < DS) {
            float bv = post_b2[n];
#pragma unroll
            for (int r = 0; r < 4; ++r)
              outS[((size_t)d * 64 + 16 * w + quad * 4 + r) * DS + n] =
                  a2[j][r] + bv;
          }
        }
      }
      // stop logits from sh
      {
        int bb = tid >> 2, kq = tid & 3;
        float a = 0.f;
        for (int kk = 0; kk < 64; kk += 8) {
          bf16x8 v = *(const bf16x8*)&smem.post.sh[bb * LDH + kq * 64 + kk];
          const float* wp = stop_w2 + kq * 64 + kk;
#pragma unroll
          for (int j = 0; j < 8; ++j) a += bf2f((unsigned short)v[j]) * wp[j];
        }
        smem.post.red[tid] = a;
      }
      __syncthreads();
      if (tid < 64)
        outStop[(size_t)d * 64 + tid] =
            smem.post.red[tid * 4] + smem.post.red[tid * 4 + 1] +
            smem.post.red[tid * 4 + 2] + smem.post.red[tid * 4 + 3] +
            stop_b2[0];
      __syncthreads();
    }
  }
}

extern "C" void kernel_launch(void* const* d_in, const int* in_sizes, int n_in,
                              void* d_out, int out_size, void* d_ws,
                              size_t ws_size, hipStream_t stream) {
  const int* token_pad = (const int*)d_in[0];
  const int* token_len = (const int*)d_in[1];
  const float* S_true = (const float*)d_in[2];
  const float* emb = (const float*)d_in[3];
  const float* enc_Wih = (const float*)d_in[4];
  const float* enc_Whh = (const float*)d_in[5];
  const float* enc_bih = (const float*)d_in[6];
  const float* enc_bhh = (const float*)d_in[7];
  const float* dec_Wih = (const float*)d_in[8];
  const float* dec_Whh = (const float*)d_in[9];
  const float* dec_bih = (const float*)d_in[10];
  const float* dec_bhh = (const float*)d_in[11];
  const float* pre_W = (const float*)d_in[12];
  const float* pre_b = (const float*)d_in[13];
  const float* post_W1 = (const float*)d_in[14];
  const float* post_b1 = (const float*)d_in[15];
  const float* post_W2 = (const float*)d_in[16];
  const float* post_b2 = (const float*)d_in[17];
  const float* stop_W1 = (const float*)d_in[18];
  const float* stop_b1 = (const float*)d_in[19];
  const float* stop_W2 = (const float*)d_in[20];
  const float* stop_b2 = (const float*)d_in[21];

  if (ws_size < WS_NEED) return;
  char* ws = (char*)d_ws;
  unsigned* flags = (unsigned*)(ws + OFF_FLAGS);
  unsigned* gxdone = (unsigned*)(ws + OFF_GXD);
  unsigned short* hpl = (unsigned short*)(ws + OFF_HPL);
  unsigned short* whe_hi = (unsigned short*)(ws + OFF_WHE_HI);
  unsigned short* whe_lo = (unsigned short*)(ws + OFF_WHE_LO);
  unsigned short* whd_hi = (unsigned short*)(ws + OFF_WHD_HI);
  unsigned short* whd_lo = (unsigned short*)(ws + OFF_WHD_LO);
  unsigned short* wc_hi = (unsigned short*)(ws + OFF_WC_HI);
  unsigned short* wc_lo = (unsigned short*)(ws + OFF_WC_LO);
  unsigned short* w1_hi = (unsigned short*)(ws + OFF_W1_HI);
  unsigned short* w1_lo = (unsigned short*)(ws + OFF_W1_LO);
  unsigned short* w2_hi = (unsigned short*)(ws + OFF_W2_HI);
  unsigned short* w2_lo = (unsigned short*)(ws + OFF_W2_LO);
  unsigned short* sw1_hi = (unsigned short*)(ws + OFF_SW1_HI);
  unsigned short* sw1_lo = (unsigned short*)(ws + OFF_SW1_LO);
  float* emb2 = (float*)(ws + OFF_EMB2);
  float* bcomb = (float*)(ws + OFF_BCOMB);
  float* WcombF = (float*)(ws + OFF_WCF);
  unsigned short* Hbf = (unsigned short*)(ws + OFF_HBF);
  _Float16* gx = (_Float16*)(ws + OFF_GX);
  float* outS = (float*)d_out;
  float* outStop = outS + (size_t)STEPS_DEC * 64 * DS;

  hipMemsetAsync(ws + OFF_FLAGS, 0, 139264, stream);      // flags+gxdone+hpl
  hipMemsetAsync(ws + OFF_WC_HI, 0, 2359296, stream);     // wc pad cols
  hipMemsetAsync(ws + OFF_W2_HI, 0, 589824, stream);      // w2 pad rows

  prep_wcomb_kernel<<<1024, 256, 0, stream>>>(dec_Wih, pre_W, pre_b, dec_bih,
                                              dec_bhh, WcombF, bcomb);
  prep_emb2_kernel<<<148, 256, 0, stream>>>(emb, enc_Wih, enc_bih, enc_bhh,
                                            emb2);
  split_bf16_kernel<<<(1024 * 552 + 255) / 256, 256, 0, stream>>>(
      WcombF, wc_hi, wc_lo, 1024, 552, 576);
  split_bf16_kernel<<<(1024 * 256 + 255) / 256, 256, 0, stream>>>(
      dec_Whh, whd_hi, whd_lo, 1024, 256, 256);
  split_bf16_kernel<<<(1024 * 256 + 255) / 256, 256, 0, stream>>>(
      enc_Whh, whe_hi, whe_lo, 1024, 256, 256);
  split_bf16_kernel<<<(256 * 256 + 255) / 256, 256, 0, stream>>>(
      post_W1, w1_hi, w1_lo, 256, 256, 256);
  split_bf16_kernel<<<(552 * 256 + 255) / 256, 256, 0, stream>>>(
      post_W2, w2_hi, w2_lo, 552, 256, 256);
  split_bf16_kernel<<<(256 * 256 + 255) / 256, 256, 0, stream>>>(
      stop_W1, sw1_hi, sw1_lo, 256, 256, 256);

  mega_kernel<<<GRID_BLKS, 256, 0, stream>>>(
      whe_hi, whe_lo, whd_hi, whd_lo, wc_hi, wc_lo, w1_hi, w1_lo, w2_hi, w2_lo,
      sw1_hi, sw1_lo, emb2, bcomb, token_pad, token_len, S_true, post_b1,
      post_b2, stop_b1, stop_W2, stop_b2, hpl, Hbf, gx, flags, gxdone, outS,
      outStop);
}

// Round 6
// 8085.435 us; speedup vs baseline: 1.3818x; 1.3818x over previous
//
#include <hip/hip_runtime.h>

#define DH 256
#define DS 552
#define DS_PAD 576
#define NG 1024
#define LTOK 128
#define STEPS_DEC 1000
#define ST_TRUE 800
#define TOTAL_STEPS (LTOK + STEPS_DEC)
#define NREC 16
#define GRID_BLKS 128
#define NHELP (GRID_BLKS - NREC)
#define LDH 264   // hid/sh LDS stride (shorts)

typedef __attribute__((ext_vector_type(8))) short bf16x8;
typedef __attribute__((ext_vector_type(4))) float f32x4;

// ---------- workspace layout (bytes) ----------
#define OFF_FLAGS    0            // 16 flags x 256B
#define OFF_GXD      4096         // 800 x u32 (+pad)
#define OFF_HPL      8192         // h planes [2 pl][2 half][64][256] bf16 = 131072
#define OFF_WHE_HI   139264
#define OFF_WHE_LO   663552
#define OFF_WHD_HI   1187840
#define OFF_WHD_LO   1712128
#define OFF_WC_HI    2236416      // [1024][576]
#define OFF_WC_LO    3416064
#define OFF_W1_HI    4595712
#define OFF_W1_LO    4726784
#define OFF_W2_HI    4857856      // [576][256] (rows 552.. zero)
#define OFF_W2_LO    5152768
#define OFF_SW1_HI   5447680
#define OFF_SW1_LO   5578752
#define OFF_EMB2     5709824      // [148][1024] f32
#define OFF_BCOMB    6316032
#define OFF_WCF      6320128      // [1024][552] f32 scratch
#define OFF_HBF      8581120      // [1000][64][256] bf16
#define OFF_GX       41349120     // [800][64][1024] fp16
#define WS_NEED      146206720ULL

__device__ __forceinline__ unsigned short f2bf_rn(float x) {
  unsigned u = __builtin_bit_cast(unsigned, x);
  u += 0x7fffu + ((u >> 16) & 1u);
  return (unsigned short)(u >> 16);
}
__device__ __forceinline__ float bf2f(unsigned short h) {
  unsigned u = ((unsigned)h) << 16;
  return __builtin_bit_cast(float, u);
}
__device__ __forceinline__ f32x4 mfma16(bf16x8 a, bf16x8 b, f32x4 c) {
  return __builtin_amdgcn_mfma_f32_16x16x32_bf16(a, b, c, 0, 0, 0);
}

// ---------- agent-scope (MALL) helpers -- proven in rounds 2/5 ----------
__device__ __forceinline__ unsigned long long ald8(const void* p) {
  return __hip_atomic_load((unsigned long long*)p, __ATOMIC_RELAXED,
                           __HIP_MEMORY_SCOPE_AGENT);
}
__device__ __forceinline__ void ast8(void* p, unsigned long long v) {
  __hip_atomic_store((unsigned long long*)p, v, __ATOMIC_RELAXED,
                     __HIP_MEMORY_SCOPE_AGENT);
}
__device__ __forceinline__ bf16x8 ald16v(const unsigned short* p) {
  union { unsigned long long u[2]; bf16x8 v; } t;
  t.u[0] = ald8(p);
  t.u[1] = ald8(p + 4);
  return t.v;
}

// ---------- prep kernels (unchanged) ----------
__global__ __launch_bounds__(256) void prep_wcomb_kernel(
    const float* __restrict__ Wih, const float* __restrict__ preW,
    const float* __restrict__ pre_b, const float* __restrict__ bih,
    const float* __restrict__ bhh, float* __restrict__ WcombF,
    float* __restrict__ bcomb) {
  __shared__ float row[DH];
  __shared__ float red[256];
  int g = blockIdx.x, tid = threadIdx.x;
  row[tid] = Wih[g * DH + tid];
  __syncthreads();
  float a0 = 0.f, a1 = 0.f, a2 = 0.f;
  for (int j = 0; j < DH; ++j) {
    float wv = row[j];
    const float* pr = preW + j * DS;
    a0 += wv * pr[tid];
    a1 += wv * pr[tid + 256];
    if (tid < DS - 512) a2 += wv * pr[tid + 512];
  }
  WcombF[g * DS + tid] = a0;
  WcombF[g * DS + tid + 256] = a1;
  if (tid < DS - 512) WcombF[g * DS + tid + 512] = a2;
  red[tid] = row[tid] * pre_b[tid];
  __syncthreads();
  for (int s = 128; s > 0; s >>= 1) {
    if (tid < s) red[tid] += red[tid + s];
    __syncthreads();
  }
  if (tid == 0) bcomb[g] = red[0] + bih[g] + bhh[g];
}

__global__ __launch_bounds__(256) void prep_emb2_kernel(
    const float* __restrict__ emb, const float* __restrict__ Wih,
    const float* __restrict__ bih, const float* __restrict__ bhh,
    float* __restrict__ emb2) {
  __shared__ float erow[DH];
  int v = blockIdx.x, tid = threadIdx.x;
  erow[tid] = emb[v * DH + tid];
  __syncthreads();
  for (int c = 0; c < 4; ++c) {
    int g = c * 256 + tid;
    const float* wr = Wih + g * DH;
    float acc = 0.f;
    for (int j = 0; j < DH; ++j) acc += erow[j] * wr[j];
    emb2[v * NG + g] = acc + bih[g] + bhh[g];
  }
}

__global__ void split_bf16_kernel(const float* __restrict__ src,
                                  unsigned short* __restrict__ hi,
                                  unsigned short* __restrict__ lo,
                                  int rows, int cols, int ldo) {
  int idx = blockIdx.x * 256 + threadIdx.x;
  if (idx >= rows * cols) return;
  int r = idx / cols, c = idx - r * cols;
  float x = src[idx];
  unsigned short h = f2bf_rn(x);
  hi[r * ldo + c] = h;
  lo[r * ldo + c] = f2bf_rn(x - bf2f(h));
}

// ---------- shared memory union ----------
union SharedU {
  struct { float T[64 * 65]; } ph1;   // helper phase-1 transpose buffer
  struct {
    unsigned short hid[64 * LDH];
    unsigned short sh[64 * LDH];
    float red[256];
  } post;
};

// ---------- mega kernel: 16 recurrence blocks + 112 helper blocks ----------
// Rec protocol = round-0 baseline (fences + plain loads, per-block flags,
// measured fastest).  Structural cut: swapped-operand MFMA (W as A, h as B)
// delivers all 4 gates of each cell directly into acc[j][0..3] -- no G-LDS
// exchange, one barrier per step instead of two.  Helper fences removed
// (write-through gx publish; atomic Hbf reads) so helper cache-maintenance
// no longer perturbs the rec XCDs' L2s.
__global__ __launch_bounds__(256, 1) void mega_kernel(
    const unsigned short* __restrict__ whe_hi, const unsigned short* __restrict__ whe_lo,
    const unsigned short* __restrict__ whd_hi, const unsigned short* __restrict__ whd_lo,
    const unsigned short* __restrict__ wc_hi, const unsigned short* __restrict__ wc_lo,
    const unsigned short* __restrict__ w1_hi, const unsigned short* __restrict__ w1_lo,
    const unsigned short* __restrict__ w2_hi, const unsigned short* __restrict__ w2_lo,
    const unsigned short* __restrict__ sw1_hi, const unsigned short* __restrict__ sw1_lo,
    const float* __restrict__ emb2, const float* __restrict__ bcomb,
    const int* __restrict__ token_pad, const int* __restrict__ token_len,
    const float* __restrict__ Strue,
    const float* __restrict__ post_b1, const float* __restrict__ post_b2,
    const float* __restrict__ stop_b1, const float* __restrict__ stop_w2,
    const float* __restrict__ stop_b2,
    unsigned short* __restrict__ hpl, unsigned short* __restrict__ Hbf,
    _Float16* __restrict__ gx, unsigned* flags, unsigned* gxdone,
    float* __restrict__ outS, float* __restrict__ outStop) {
  __shared__ SharedU smem;
  int tid = threadIdx.x;
  int w = tid >> 6, lane = tid & 63, quad = lane >> 4, lrow = lane & 15;

  if (blockIdx.x < NREC) {
    // ================= persistent recurrence =================
    int rb = blockIdx.x;
    int b = 16 * w + lrow;        // batch column owned by this thread
    int gub = 16 * rb + 4 * quad; // 4 consecutive units per thread
    int len = token_len[b];
    float bc[16];
#pragma unroll
    for (int i = 0; i < 4; ++i)
#pragma unroll
      for (int g = 0; g < 4; ++g) bc[i * 4 + g] = bcomb[g * 256 + gub + i];
    // Weight A-frags in VGPRs.  Row map for tile j, frag-row m (=lrow):
    //   W row = (m&3)*256 + 16rb + 4*(m>>2) + j
    // => C row 4q+r of tile j = gate r of unit 16rb+4q+j  (cells in-register)
    int grow0 = (lrow & 3) * 256 + 16 * rb + 4 * (lrow >> 2);
    bf16x8 Bh[4][8], Bl[4][8];
#pragma unroll
    for (int j = 0; j < 4; ++j)
#pragma unroll
      for (int ks = 0; ks < 8; ++ks) {
        size_t off = (size_t)(grow0 + j) * DH + ks * 32 + quad * 8;
        Bh[j][ks] = *(const bf16x8*)(whe_hi + off);
        Bl[j][ks] = *(const bf16x8*)(whe_lo + off);
      }
    float c[4] = {0.f, 0.f, 0.f, 0.f}, h[4] = {0.f, 0.f, 0.f, 0.f};
    float xc[16], xn[16];
    {  // x for S=0 (encoder)
      int tok = token_pad[b];
#pragma unroll
      for (int g = 0; g < 4; ++g) {
        float4 e = *(const float4*)(emb2 + (size_t)tok * NG + g * 256 + gub);
        xc[0 * 4 + g] = e.x; xc[1 * 4 + g] = e.y;
        xc[2 * 4 + g] = e.z; xc[3 * 4 + g] = e.w;
      }
    }
    int gxwm = 0;
    for (int S = 0; S < TOTAL_STEPS; ++S) {
      if (S == LTOK) {  // swap to decoder weights; (h,c) = (enc_out, enc_out)
#pragma unroll
        for (int j = 0; j < 4; ++j)
#pragma unroll
          for (int ks = 0; ks < 8; ++ks) {
            size_t off = (size_t)(grow0 + j) * DH + ks * 32 + quad * 8;
            Bh[j][ks] = *(const bf16x8*)(whd_hi + off);
            Bl[j][ks] = *(const bf16x8*)(whd_lo + off);
          }
#pragma unroll
        for (int i = 0; i < 4; ++i) c[i] = h[i];
      }
      int dn = S + 1 - LTOK;  // decoder index of NEXT step's x
      // 1. gx readiness (uniform; no-op once helpers are ahead)
      if (dn >= 1 && dn < ST_TRUE) {
        while (gxwm < dn) {
          if (__hip_atomic_load(&gxdone[gxwm + 1], __ATOMIC_RELAXED,
                                __HIP_MEMORY_SCOPE_AGENT) >= 16u)
            ++gxwm;
          else
            __builtin_amdgcn_s_sleep(1);
        }
      }
      // 2. peer h flags >= S  (round-0 layout: 16 flags, 256B apart)
      {
        const unsigned* fp = &flags[(lane & 15) * 64];
        unsigned tgt = (unsigned)S;
        for (;;) {
          unsigned f =
              __hip_atomic_load(fp, __ATOMIC_RELAXED, __HIP_MEMORY_SCOPE_AGENT);
          if (__all(f >= tgt)) break;
          __builtin_amdgcn_s_sleep(1);
        }
      }
      __builtin_amdgcn_fence(__ATOMIC_ACQUIRE, "agent");
      // 3. prefetch x for step S+1 (consumed next iteration)
      if (S + 1 < LTOK) {
        int tok = token_pad[(S + 1) * 64 + b];
#pragma unroll
        for (int g = 0; g < 4; ++g) {
          float4 e = *(const float4*)(emb2 + (size_t)tok * NG + g * 256 + gub);
          xn[0 * 4 + g] = e.x; xn[1 * 4 + g] = e.y;
          xn[2 * 4 + g] = e.z; xn[3 * 4 + g] = e.w;
        }
      } else if (dn >= 1 && dn < ST_TRUE) {
        const _Float16* gp = gx + ((size_t)dn * 64 + b) * NG;
#pragma unroll
        for (int g = 0; g < 4; ++g) {
          union { unsigned long long u; _Float16 f[4]; } t;
          t.u = ald8(gp + g * 256 + gub);
#pragma unroll
          for (int i = 0; i < 4; ++i) xn[i * 4 + g] = (float)t.f[i];
        }
      } else {
#pragma unroll
        for (int k = 0; k < 16; ++k) xn[k] = 0.f;
      }
      // 4. h B-frags (hi/lo), plain coalesced loads (addresses unchanged)
      const unsigned short* hb = hpl + ((S & 1) << 15);
      int arow = w * 16 + lrow;
      bf16x8 Ah[8], Al[8];
#pragma unroll
      for (int ks = 0; ks < 8; ++ks) {
        Ah[ks] = *(const bf16x8*)(hb + arow * 256 + ks * 32 + quad * 8);
        Al[ks] = *(const bf16x8*)(hb + 16384 + arow * 256 + ks * 32 + quad * 8);
      }
      // 5. MFMA, swapped operands: G^T = W * h^T, 3-term split.
      // Same k-products in the same order as before -> bit-identical sums.
      f32x4 acc[4];
#pragma unroll
      for (int j = 0; j < 4; ++j) acc[j] = (f32x4){0.f, 0.f, 0.f, 0.f};
#pragma unroll
      for (int ks = 0; ks < 8; ++ks)
#pragma unroll
        for (int j = 0; j < 4; ++j) {
          acc[j] = mfma16(Bh[j][ks], Ah[ks], acc[j]);
          acc[j] = mfma16(Bh[j][ks], Al[ks], acc[j]);
          acc[j] = mfma16(Bl[j][ks], Ah[ks], acc[j]);
        }
      // 6. nonlinearity fully in-register: acc[i][r] = gate r of cell
      //    (b, gub+i).  No LDS, no barrier.
      unsigned hv0, hv1, lv0, lv1;
      {
        unsigned short hhs[4], hls[4];
#pragma unroll
        for (int i = 0; i < 4; ++i) {
          float gI = acc[i][0];
          float gF = acc[i][1];
          float gG = acc[i][2];
          float gO = acc[i][3];
          if (S < LTOK) {
            gI += xc[i * 4 + 0]; gF += xc[i * 4 + 1];
            gG += xc[i * 4 + 2]; gO += xc[i * 4 + 3];
          } else {
            gI += bc[i * 4 + 0] + xc[i * 4 + 0];
            gF += bc[i * 4 + 1] + xc[i * 4 + 1];
            gG += bc[i * 4 + 2] + xc[i * 4 + 2];
            gO += bc[i * 4 + 3] + xc[i * 4 + 3];
          }
          float si = 1.f / (1.f + expf(-gI));
          float sf = 1.f / (1.f + expf(-gF));
          float so = 1.f / (1.f + expf(-gO));
          float c2 = sf * c[i] + si * tanhf(gG);
          float h2 = so * tanhf(c2);
          if (S < LTOK && S >= len) { c2 = c[i]; h2 = h[i]; }
          c[i] = c2; h[i] = h2;
          unsigned short hh = f2bf_rn(h2);
          hhs[i] = hh;
          hls[i] = f2bf_rn(h2 - bf2f(hh));
        }
        hv0 = (unsigned)hhs[0] | ((unsigned)hhs[1] << 16);
        hv1 = (unsigned)hhs[2] | ((unsigned)hhs[3] << 16);
        lv0 = (unsigned)hls[0] | ((unsigned)hls[1] << 16);
        lv1 = (unsigned)hls[2] | ((unsigned)hls[3] << 16);
      }
      // 7. publish h (packed 8B chunks, plain stores) + Hbf
      unsigned short* ob = hpl + (((S & 1) ^ 1) << 15);
      *(uint2*)&ob[b * 256 + gub] = make_uint2(hv0, hv1);
      *(uint2*)&ob[16384 + b * 256 + gub] = make_uint2(lv0, lv1);
      if (S >= LTOK) {
        int d = S - LTOK;
        *(uint2*)&Hbf[((size_t)d * 64 + b) * 256 + gub] = make_uint2(hv0, hv1);
      }
#pragma unroll
      for (int k = 0; k < 16; ++k) xc[k] = xn[k];
      // 8. single barrier drains each wave's vmcnt; tid0 flushes L2 (release)
      //    and publishes the block flag -- round-0 proven pattern.
      __syncthreads();
      if (tid == 0) {
        __builtin_amdgcn_fence(__ATOMIC_RELEASE, "agent");
        __hip_atomic_store(&flags[rb * 64], (unsigned)(S + 1), __ATOMIC_RELAXED,
                           __HIP_MEMORY_SCOPE_AGENT);
      }
    }
  } else {
    // ================= helpers =================
    int hid0 = blockIdx.x - NREC;
    // ---- phase 1: gx tiles (t ascending) ----
    // Publish via write-through 8B agent stores (LDS repack) -- no release
    // fence, so helper XCD L2s are never flushed (rec blocks co-located on
    // those XCDs keep their pipelines clean).
    for (int item = hid0; item < 799 * 16; item += NHELP) {
      int t = 1 + (item >> 4);
      int n0 = (item & 15) << 6;
      f32x4 acc[4];
#pragma unroll
      for (int j = 0; j < 4; ++j) acc[j] = (f32x4){0.f, 0.f, 0.f, 0.f};
      for (int ks = 0; ks < 18; ++ks) {
        int kb = ks * 32 + quad * 8;
        bf16x8 ah, al;
        if (kb < DS) {
          const float* ap = Strue + ((size_t)t * 64 + w * 16 + lrow) * DS + kb;
          float4 x0 = *(const float4*)ap;
          float4 x1 = *(const float4*)(ap + 4);
          float xs[8] = {x0.x, x0.y, x0.z, x0.w, x1.x, x1.y, x1.z, x1.w};
#pragma unroll
          for (int j = 0; j < 8; ++j) {
            unsigned u = __builtin_bit_cast(unsigned, xs[j]);
            unsigned short hh = (unsigned short)(u >> 16);
            ah[j] = (short)hh;
            al[j] = (short)f2bf_rn(xs[j] - bf2f(hh));
          }
        } else {
#pragma unroll
          for (int j = 0; j < 8; ++j) { ah[j] = 0; al[j] = 0; }
        }
#pragma unroll
        for (int j = 0; j < 4; ++j) {
          int n = n0 + j * 16 + lrow;
          bf16x8 bh = *(const bf16x8*)(wc_hi + (size_t)n * DS_PAD + kb);
          bf16x8 bl = *(const bf16x8*)(wc_lo + (size_t)n * DS_PAD + kb);
          acc[j] = mfma16(ah, bh, acc[j]);
          acc[j] = mfma16(al, bh, acc[j]);
          acc[j] = mfma16(ah, bl, acc[j]);
        }
      }
      // stage into LDS (f32, exact), then repack rows and publish as 8B
      // write-through chunks
      float* T = smem.ph1.T;
#pragma unroll
      for (int j = 0; j < 4; ++j)
#pragma unroll
        for (int r = 0; r < 4; ++r)
          T[(w * 16 + quad * 4 + r) * 65 + j * 16 + lrow] = acc[j][r];
      __syncthreads();
      {
        int r0 = tid & 63, cg = tid >> 6;  // row, col-group of 16
        const float* src = &T[r0 * 65 + cg * 16];
        _Float16* gp = gx + ((size_t)t * 64 + r0) * NG + n0 + cg * 16;
#pragma unroll
        for (int m = 0; m < 4; ++m) {
          union { unsigned long long u; _Float16 f[4]; } pk;
#pragma unroll
          for (int k = 0; k < 4; ++k) pk.f[k] = (_Float16)src[m * 4 + k];
          ast8(gp + m * 4, pk.u);
        }
      }
      __syncthreads();  // drains vmcnt: 8B chunks are at the coherence point
      if (tid == 0)
        __hip_atomic_fetch_add(&gxdone[t], 1u, __ATOMIC_RELAXED,
                               __HIP_MEMORY_SCOPE_AGENT);
      __syncthreads();
    }
    // ---- phase 2: post-nets per decoder step ----
    // No acquire fence: Hbf read via agent atomics (round-2 proven), so
    // w1/w2/sw1 stay L2-resident across steps.
    for (int d = hid0; d < STEPS_DEC; d += NHELP) {
      unsigned tgt = (unsigned)(LTOK + d + 1);
      {
        const unsigned* fp = &flags[(lane & 15) * 64];
        for (;;) {
          unsigned f =
              __hip_atomic_load(fp, __ATOMIC_RELAXED, __HIP_MEMORY_SCOPE_AGENT);
          if (__all(f >= tgt)) break;
          __builtin_amdgcn_s_sleep(8);
        }
      }
      asm volatile("" ::: "memory");
      bf16x8 Af[8];
#pragma unroll
      for (int ks = 0; ks < 8; ++ks)
        Af[ks] = ald16v(Hbf + ((size_t)d * 64 + w * 16 + lrow) * 256 +
                        ks * 32 + quad * 8);
      // W1 -> hid (LDS), relu, bf16
      {
        f32x4 a1[16];
#pragma unroll
        for (int j = 0; j < 16; ++j) a1[j] = (f32x4){0.f, 0.f, 0.f, 0.f};
        for (int ks = 0; ks < 8; ++ks) {
          int kb = ks * 32 + quad * 8;
#pragma unroll
          for (int j = 0; j < 16; ++j) {
            int n = j * 16 + lrow;
            bf16x8 bh = *(const bf16x8*)(w1_hi + (size_t)n * DH + kb);
            bf16x8 bl = *(const bf16x8*)(w1_lo + (size_t)n * DH + kb);
            a1[j] = mfma16(Af[ks], bh, a1[j]);
            a1[j] = mfma16(Af[ks], bl, a1[j]);
          }
        }
#pragma unroll
        for (int j = 0; j < 16; ++j) {
          int n = j * 16 + lrow;
          float bv = post_b1[n];
#pragma unroll
          for (int r = 0; r < 4; ++r) {
            float v = fmaxf(a1[j][r] + bv, 0.f);
            smem.post.hid[(16 * w + quad * 4 + r) * LDH + n] = f2bf_rn(v);
          }
        }
        // SW1 -> sh (LDS)
#pragma unroll
        for (int j = 0; j < 16; ++j) a1[j] = (f32x4){0.f, 0.f, 0.f, 0.f};
        for (int ks = 0; ks < 8; ++ks) {
          int kb = ks * 32 + quad * 8;
#pragma unroll
          for (int j = 0; j < 16; ++j) {
            int n = j * 16 + lrow;
            bf16x8 bh = *(const bf16x8*)(sw1_hi + (size_t)n * DH + kb);
            bf16x8 bl = *(const bf16x8*)(sw1_lo + (size_t)n * DH + kb);
            a1[j] = mfma16(Af[ks], bh, a1[j]);
            a1[j] = mfma16(Af[ks], bl, a1[j]);
          }
        }
#pragma unroll
        for (int j = 0; j < 16; ++j) {
          int n = j * 16 + lrow;
          float bv = stop_b1[n];
#pragma unroll
          for (int r = 0; r < 4; ++r) {
            float v = fmaxf(a1[j][r] + bv, 0.f);
            smem.post.sh[(16 * w + quad * 4 + r) * LDH + n] = f2bf_rn(v);
          }
        }
      }
      __syncthreads();
      // W2: hid @ W2^T + b2 -> outS (fp32)
      {
        bf16x8 Hf[8];
#pragma unroll
        for (int ks = 0; ks < 8; ++ks)
          Hf[ks] = *(const bf16x8*)&smem.post
                        .hid[(16 * w + lrow) * LDH + ks * 32 + quad * 8];
        f32x4 a2[36];
#pragma unroll
        for (int j = 0; j < 36; ++j) a2[j] = (f32x4){0.f, 0.f, 0.f, 0.f};
        for (int ks = 0; ks < 8; ++ks) {
          int kb = ks * 32 + quad * 8;
#pragma unroll
          for (int j = 0; j < 36; ++j) {
            int n = j * 16 + lrow;
            bf16x8 bh = *(const bf16x8*)(w2_hi + (size_t)n * DH + kb);
            bf16x8 bl = *(const bf16x8*)(w2_lo + (size_t)n * DH + kb);
            a2[j] = mfma16(Hf[ks], bh, a2[j]);
            a2[j] = mfma16(Hf[ks], bl, a2[j]);
          }
        }
#pragma unroll
        for (int j = 0; j < 36; ++j) {
          int n = j * 16 + lrow;
          if (n < DS) {
            float bv = post_b2[n];
#pragma unroll
            for (int r = 0; r < 4; ++r)
              outS[((size_t)d * 64 + 16 * w + quad * 4 + r) * DS + n] =
                  a2[j][r] + bv;
          }
        }
      }
      // stop logits from sh
      {
        int bb = tid >> 2, kq = tid & 3;
        float a = 0.f;
        for (int kk = 0; kk < 64; kk += 8) {
          bf16x8 v = *(const bf16x8*)&smem.post.sh[bb * LDH + kq * 64 + kk];
          const float* wp = stop_w2 + kq * 64 + kk;
#pragma unroll
          for (int j = 0; j < 8; ++j) a += bf2f((unsigned short)v[j]) * wp[j];
        }
        smem.post.red[tid] = a;
      }
      __syncthreads();
      if (tid < 64)
        outStop[(size_t)d * 64 + tid] =
            smem.post.red[tid * 4] + smem.post.red[tid * 4 + 1] +
            smem.post.red[tid * 4 + 2] + smem.post.red[tid * 4 + 3] +
            stop_b2[0];
      __syncthreads();
    }
  }
}

extern "C" void kernel_launch(void* const* d_in, const int* in_sizes, int n_in,
                              void* d_out, int out_size, void* d_ws,
                              size_t ws_size, hipStream_t stream) {
  const int* token_pad = (const int*)d_in[0];
  const int* token_len = (const int*)d_in[1];
  const float* S_true = (const float*)d_in[2];
  const float* emb = (const float*)d_in[3];
  const float* enc_Wih = (const float*)d_in[4];
  const float* enc_Whh = (const float*)d_in[5];
  const float* enc_bih = (const float*)d_in[6];
  const float* enc_bhh = (const float*)d_in[7];
  const float* dec_Wih = (const float*)d_in[8];
  const float* dec_Whh = (const float*)d_in[9];
  const float* dec_bih = (const float*)d_in[10];
  const float* dec_bhh = (const float*)d_in[11];
  const float* pre_W = (const float*)d_in[12];
  const float* pre_b = (const float*)d_in[13];
  const float* post_W1 = (const float*)d_in[14];
  const float* post_b1 = (const float*)d_in[15];
  const float* post_W2 = (const float*)d_in[16];
  const float* post_b2 = (const float*)d_in[17];
  const float* stop_W1 = (const float*)d_in[18];
  const float* stop_b1 = (const float*)d_in[19];
  const float* stop_W2 = (const float*)d_in[20];
  const float* stop_b2 = (const float*)d_in[21];

  if (ws_size < WS_NEED) return;
  char* ws = (char*)d_ws;
  unsigned* flags = (unsigned*)(ws + OFF_FLAGS);
  unsigned* gxdone = (unsigned*)(ws + OFF_GXD);
  unsigned short* hpl = (unsigned short*)(ws + OFF_HPL);
  unsigned short* whe_hi = (unsigned short*)(ws + OFF_WHE_HI);
  unsigned short* whe_lo = (unsigned short*)(ws + OFF_WHE_LO);
  unsigned short* whd_hi = (unsigned short*)(ws + OFF_WHD_HI);
  unsigned short* whd_lo = (unsigned short*)(ws + OFF_WHD_LO);
  unsigned short* wc_hi = (unsigned short*)(ws + OFF_WC_HI);
  unsigned short* wc_lo = (unsigned short*)(ws + OFF_WC_LO);
  unsigned short* w1_hi = (unsigned short*)(ws + OFF_W1_HI);
  unsigned short* w1_lo = (unsigned short*)(ws + OFF_W1_LO);
  unsigned short* w2_hi = (unsigned short*)(ws + OFF_W2_HI);
  unsigned short* w2_lo = (unsigned short*)(ws + OFF_W2_LO);
  unsigned short* sw1_hi = (unsigned short*)(ws + OFF_SW1_HI);
  unsigned short* sw1_lo = (unsigned short*)(ws + OFF_SW1_LO);
  float* emb2 = (float*)(ws + OFF_EMB2);
  float* bcomb = (float*)(ws + OFF_BCOMB);
  float* WcombF = (float*)(ws + OFF_WCF);
  unsigned short* Hbf = (unsigned short*)(ws + OFF_HBF);
  _Float16* gx = (_Float16*)(ws + OFF_GX);
  float* outS = (float*)d_out;
  float* outStop = outS + (size_t)STEPS_DEC * 64 * DS;

  hipMemsetAsync(ws + OFF_FLAGS, 0, 139264, stream);      // flags+gxdone+hpl
  hipMemsetAsync(ws + OFF_WC_HI, 0, 2359296, stream);     // wc pad cols
  hipMemsetAsync(ws + OFF_W2_HI, 0, 589824, stream);      // w2 pad rows

  prep_wcomb_kernel<<<1024, 256, 0, stream>>>(dec_Wih, pre_W, pre_b, dec_bih,
                                              dec_bhh, WcombF, bcomb);
  prep_emb2_kernel<<<148, 256, 0, stream>>>(emb, enc_Wih, enc_bih, enc_bhh,
                                            emb2);
  split_bf16_kernel<<<(1024 * 552 + 255) / 256, 256, 0, stream>>>(
      WcombF, wc_hi, wc_lo, 1024, 552, 576);
  split_bf16_kernel<<<(1024 * 256 + 255) / 256, 256, 0, stream>>>(
      dec_Whh, whd_hi, whd_lo, 1024, 256, 256);
  split_bf16_kernel<<<(1024 * 256 + 255) / 256, 256, 0, stream>>>(
      enc_Whh, whe_hi, whe_lo, 1024, 256, 256);
  split_bf16_kernel<<<(256 * 256 + 255) / 256, 256, 0, stream>>>(
      post_W1, w1_hi, w1_lo, 256, 256, 256);
  split_bf16_kernel<<<(552 * 256 + 255) / 256, 256, 0, stream>>>(
      post_W2, w2_hi, w2_lo, 552, 256, 256);
  split_bf16_kernel<<<(256 * 256 + 255) / 256, 256, 0, stream>>>(
      stop_W1, sw1_hi, sw1_lo, 256, 256, 256);

  mega_kernel<<<GRID_BLKS, 256, 0, stream>>>(
      whe_hi, whe_lo, whd_hi, whd_lo, wc_hi, wc_lo, w1_hi, w1_lo, w2_hi, w2_lo,
      sw1_hi, sw1_lo, emb2, bcomb, token_pad, token_len, S_true, post_b1,
      post_b2, stop_b1, stop_W2, stop_b2, hpl, Hbf, gx, flags, gxdone, outS,
      outStop);
}